// Round 12
// baseline (354.187 us; speedup 1.0000x reference)
//
#include <hip/hip_runtime.h>
#include <math.h>

#define N_NODES 100000
#define N_EDGES 1600000
#define OUTC 40
#define PAIRS40 20

#define NC 32                       // edge chunks
#define CHUNK (N_EDGES / NC)        // 50000 exact

// histogram pass: 16-bit packed counters, 32768 nodes/range
#define RANGE_H 32768
#define NR_H 4                      // 4*32768 = 131072 >= N
#define NPAD_H (NR_H * RANGE_H)     // 131072

// fill pass: 32-bit position counters, 16384 nodes/range
#define RANGE_F 16384
#define NR_F 7                      // 7*16384 = 114688 >= N

#define SCAN_BLOCK 1024
#define SCAN_NBLK ((N_NODES + SCAN_BLOCK - 1) / SCAN_BLOCK)   // 98

typedef float vf2 __attribute__((ext_vector_type(2)));

__device__ inline unsigned pack_bf16x2(float lo, float hi) {
    unsigned a = __float_as_uint(lo), b = __float_as_uint(hi);
    a = (a + 0x7fffu + ((a >> 16) & 1u)) >> 16;
    b = (b + 0x7fffu + ((b >> 16) & 1u)) & 0xffff0000u;
    return a | b;
}
__device__ inline float bf_lo(unsigned u) { return __uint_as_float(u << 16); }
__device__ inline float bf_hi(unsigned u) { return __uint_as_float(u & 0xffff0000u); }

// ---------------- histogram: packed 16-bit LDS counters ----------------
__global__ __launch_bounds__(1024) void k_hist(const int* __restrict__ src,
                                               const int* __restrict__ dst,
                                               int* __restrict__ Hs,
                                               int* __restrict__ Hd) {
    __shared__ unsigned h32[RANGE_H / 2];    // 64 KB
    int c = blockIdx.x, r = blockIdx.y;
    const int* a = blockIdx.z ? dst : src;
    int* H = blockIdx.z ? Hd : Hs;
    for (int k = threadIdx.x; k < RANGE_H / 2; k += 1024) h32[k] = 0;
    __syncthreads();
    int r0 = r * RANGE_H;
    int e0 = c * CHUNK, e1 = e0 + CHUNK;
    for (int e = e0 + threadIdx.x; e < e1; e += 1024) {
        unsigned d = (unsigned)(a[e] - r0);
        if (d < RANGE_H) atomicAdd(&h32[d >> 1], 1u << ((d & 1) * 16));
    }
    __syncthreads();
    for (int k = threadIdx.x; k < RANGE_H; k += 1024)
        H[c * NPAD_H + r0 + k] = (int)((h32[k >> 1] >> ((k & 1) * 16)) & 0xffffu);
}

// scan1: deg_src/maxdeg from Hs; inclusive scan of PADDED deg_dst -> rowptr[i+1]
__global__ __launch_bounds__(SCAN_BLOCK) void k_scan1(const int* __restrict__ Hs,
                                                      const int* __restrict__ Hd,
                                                      int* __restrict__ rowptr,
                                                      int* __restrict__ blocksum,
                                                      int* __restrict__ deg_src,
                                                      int* __restrict__ maxdeg) {
    __shared__ int buf[2][SCAN_BLOCK];
    int t = threadIdx.x;
    int i = blockIdx.x * SCAN_BLOCK + t;
    int vs = 0, vd = 0;
    if (i < N_NODES) {
        #pragma unroll
        for (int c = 0; c < NC; c++) { vs += Hs[c * NPAD_H + i]; vd += Hd[c * NPAD_H + i]; }
        deg_src[i] = vs;
    }
    int m = vs;
    for (int off = 32; off; off >>= 1) m = max(m, __shfl_down(m, off));
    if ((t & 63) == 0) atomicMax(maxdeg, m);
    int pd = (vd + 7) & ~7;                  // pad each node's slot count to x8
    int cur = 0;
    buf[0][t] = pd;
    __syncthreads();
    for (int off = 1; off < SCAN_BLOCK; off <<= 1) {
        int nv = buf[cur][t];
        if (t >= off) nv += buf[cur][t - off];
        buf[1 - cur][t] = nv;
        cur = 1 - cur;
        __syncthreads();
    }
    int incl = buf[cur][t];
    if (i < N_NODES) rowptr[i + 1] = incl;
    if (t == SCAN_BLOCK - 1) blocksum[blockIdx.x] = incl;
}

// finalize: rowptr += chunk offset; Hd -> per-chunk base positions; write pad sentinels
__global__ __launch_bounds__(SCAN_BLOCK) void k_finalize(const int* __restrict__ blocksum,
                                                         int* __restrict__ rowptr,
                                                         int* __restrict__ Hd,
                                                         int* __restrict__ csr_src) {
    __shared__ int soff;
    int t = threadIdx.x, blk = blockIdx.x;
    if (t == 0) {
        int r = 0;
        for (int j = 0; j < blk; j++) r += blocksum[j];
        soff = r;
        if (blk == 0) rowptr[0] = 0;
    }
    __syncthreads();
    int i = blk * SCAN_BLOCK + t;
    if (i >= N_NODES) return;
    int tmp[NC];
    int s = 0;
    #pragma unroll
    for (int c = 0; c < NC; c++) { tmp[c] = Hd[c * NPAD_H + i]; s += tmp[c]; }
    int rf = rowptr[i + 1] + soff;           // padded inclusive end
    rowptr[i + 1] = rf;
    int pd = (s + 7) & ~7;
    int run = rf - pd;                       // padded base
    #pragma unroll
    for (int c = 0; c < NC; c++) { Hd[c * NPAD_H + i] = run; run += tmp[c]; }
    for (int k = run; k < rf; k++) csr_src[k] = N_NODES;   // pad slots -> zero row
}

// counting-sort fill: LDS position counters, no global atomics
__global__ __launch_bounds__(1024) void k_fill2(const int* __restrict__ src,
                                                const int* __restrict__ dst,
                                                const int* __restrict__ basepos,
                                                int* __restrict__ csr_src) {
    __shared__ int pos[RANGE_F];
    int c = blockIdx.x, r = blockIdx.y;
    int r0 = r * RANGE_F;
    for (int k = threadIdx.x; k < RANGE_F; k += 1024) pos[k] = basepos[c * NPAD_H + r0 + k];
    __syncthreads();
    int e0 = c * CHUNK, e1 = e0 + CHUNK;
    for (int e = e0 + threadIdx.x; e < e1; e += 1024) {
        unsigned d = (unsigned)(dst[e] - r0);
        if (d < RANGE_F) {
            int s = src[e];
            int p = atomicAdd(&pos[d], 1);
            csr_src[p] = s;
        }
    }
}

// ---------------- GEMM 64->64 (layer 0): bf16 weights in LDS ----------------
__global__ __launch_bounds__(256) void k_gemm64(const float* __restrict__ hf,
                                                const float* __restrict__ W0,
                                                const float* __restrict__ W1,
                                                const float* __restrict__ b,
                                                const int* __restrict__ deg_src,
                                                const int* __restrict__ maxdeg,
                                                unsigned* __restrict__ G0b,
                                                unsigned short* __restrict__ G1f8) {
    __shared__ unsigned sw0[64 * 32], sw1[64 * 32];   // 16 KB (bf16x2)
    __shared__ float sh[32 * 64];                     // 8 KB
    int t = threadIdx.x;
    const float2* W02 = (const float2*)W0;
    const float2* W12 = (const float2*)W1;
    for (int k = t; k < 64 * 32; k += 256) {
        float2 w0 = W02[k], w1 = W12[k];
        sw0[k] = pack_bf16x2(w0.x, w0.y);
        sw1[k] = pack_bf16x2(w1.x, w1.y);
    }
    int i0 = blockIdx.x * 32;
    const float4* h4 = (const float4*)(hf + (size_t)i0 * 64);
    float4* sh4 = (float4*)sh;
    for (int k = t; k < 512; k += 256) sh4[k] = h4[k];
    if (blockIdx.x == 0 && t < 16) ((unsigned*)G1f8)[N_NODES * 16 + t] = 0;   // zero row
    __syncthreads();
    int c2 = t & 31, rg = t >> 5;
    float scale = 1.0f / (float)(*maxdeg);
    float2 b2 = ((const float2*)b)[c2];
    float a0x[4], a0y[4], a1x[4], a1y[4];
    #pragma unroll
    for (int p = 0; p < 4; p++) { a0x[p] = b2.x; a0y[p] = b2.y; a1x[p] = 0.f; a1y[p] = 0.f; }
    #pragma unroll
    for (int k = 0; k < 64; k++) {
        unsigned u0 = sw0[k * 32 + c2], u1 = sw1[k * 32 + c2];
        float w0x = bf_lo(u0), w0y = bf_hi(u0), w1x = bf_lo(u1), w1y = bf_hi(u1);
        #pragma unroll
        for (int p = 0; p < 4; p++) {
            float hv = sh[(rg + 8 * p) * 64 + k];
            a0x[p] += hv * w0x; a0y[p] += hv * w0y;
            a1x[p] += hv * w1x; a1y[p] += hv * w1y;
        }
    }
    #pragma unroll
    for (int p = 0; p < 4; p++) {
        int row = i0 + rg + 8 * p;
        float nl = (float)deg_src[row] * scale - 1.0f;
        G0b[row * 32 + c2] = pack_bf16x2(a0x[p] + nl * a1x[p], a0y[p] + nl * a1y[p]);
        int pk = __builtin_amdgcn_cvt_pk_fp8_f32(a1x[p], a1y[p], 0, false);
        G1f8[row * 32 + c2] = (unsigned short)(pk & 0xffff);
    }
}

// ---------------- fused spmm64+relu + gemm64 (next layer), bf16 weights in LDS ----------------
__global__ __launch_bounds__(256) void k_fs64_g64(const unsigned* __restrict__ G0b_in,
                                                  const unsigned char* __restrict__ g1_in,
                                                  const int* __restrict__ rowptr,
                                                  const int* __restrict__ csr_src,
                                                  const int* __restrict__ deg_src,
                                                  const int* __restrict__ maxdeg,
                                                  const float* __restrict__ W0,
                                                  const float* __restrict__ W1,
                                                  const float* __restrict__ b,
                                                  unsigned* __restrict__ G0b_out,
                                                  unsigned short* __restrict__ G1f8_out) {
    __shared__ unsigned sw0[64 * 32], sw1[64 * 32];   // 16 KB
    __shared__ float sh[32 * 64];                     // 8 KB  -> 24 KB total
    int t = threadIdx.x;
    const float2* W02 = (const float2*)W0;
    const float2* W12 = (const float2*)W1;
    for (int k = t; k < 64 * 32; k += 256) {
        float2 w0 = W02[k], w1 = W12[k];
        sw0[k] = pack_bf16x2(w0.x, w0.y);
        sw1[k] = pack_bf16x2(w1.x, w1.y);
    }
    // ---- spmm part ----
    int waveId = t >> 6, lane = t & 63;
    int ch = lane & 7;
    int local = waveId * 8 + (lane >> 3);
    int node = blockIdx.x * 32 + local;
    float scale = 1.0f / (float)(*maxdeg);
    int e0 = rowptr[node], e1 = rowptr[node + 1];   // multiple of 8
    int octbase = lane & 56;
    vf2 acc[4];
    acc[0] = 0.f; acc[1] = 0.f; acc[2] = 0.f; acc[3] = 0.f;
    for (int e = e0; e < e1; e += 8) {
        int idx = csr_src[e + ch];                  // always valid (padded)
        #pragma unroll
        for (int j = 0; j < 8; j++) {
            int s = __shfl(idx, octbase | j);
            uint2 u = ((const uint2*)(g1_in + (size_t)s * 64))[ch];
            acc[0] += __builtin_amdgcn_cvt_pk_f32_fp8((int)u.x, false);
            acc[1] += __builtin_amdgcn_cvt_pk_f32_fp8((int)u.x, true);
            acc[2] += __builtin_amdgcn_cvt_pk_f32_fp8((int)u.y, false);
            acc[3] += __builtin_amdgcn_cvt_pk_f32_fp8((int)u.y, true);
        }
    }
    uint4 g = ((const uint4*)(G0b_in + (size_t)node * 32))[ch];
    float* shr = sh + local * 64 + ch * 8;
    shr[0] = fmaxf(bf_lo(g.x) - scale * acc[0].x, 0.f);
    shr[1] = fmaxf(bf_hi(g.x) - scale * acc[0].y, 0.f);
    shr[2] = fmaxf(bf_lo(g.y) - scale * acc[1].x, 0.f);
    shr[3] = fmaxf(bf_hi(g.y) - scale * acc[1].y, 0.f);
    shr[4] = fmaxf(bf_lo(g.z) - scale * acc[2].x, 0.f);
    shr[5] = fmaxf(bf_hi(g.z) - scale * acc[2].y, 0.f);
    shr[6] = fmaxf(bf_lo(g.w) - scale * acc[3].x, 0.f);
    shr[7] = fmaxf(bf_hi(g.w) - scale * acc[3].y, 0.f);
    if (blockIdx.x == 0 && t < 16) ((unsigned*)G1f8_out)[N_NODES * 16 + t] = 0;  // zero row
    __syncthreads();
    // ---- gemm part ----
    int c2 = t & 31, rg = t >> 5;
    int i0 = blockIdx.x * 32;
    float2 b2 = ((const float2*)b)[c2];
    float a0x[4], a0y[4], a1x[4], a1y[4];
    #pragma unroll
    for (int p = 0; p < 4; p++) { a0x[p] = b2.x; a0y[p] = b2.y; a1x[p] = 0.f; a1y[p] = 0.f; }
    #pragma unroll
    for (int k = 0; k < 64; k++) {
        unsigned u0 = sw0[k * 32 + c2], u1 = sw1[k * 32 + c2];
        float w0x = bf_lo(u0), w0y = bf_hi(u0), w1x = bf_lo(u1), w1y = bf_hi(u1);
        #pragma unroll
        for (int p = 0; p < 4; p++) {
            float hv = sh[(rg + 8 * p) * 64 + k];
            a0x[p] += hv * w0x; a0y[p] += hv * w0y;
            a1x[p] += hv * w1x; a1y[p] += hv * w1y;
        }
    }
    #pragma unroll
    for (int p = 0; p < 4; p++) {
        int row = i0 + rg + 8 * p;
        float nl = (float)deg_src[row] * scale - 1.0f;
        G0b_out[row * 32 + c2] = pack_bf16x2(a0x[p] + nl * a1x[p], a0y[p] + nl * a1y[p]);
        int pk = __builtin_amdgcn_cvt_pk_fp8_f32(a1x[p], a1y[p], 0, false);
        G1f8_out[row * 32 + c2] = (unsigned short)(pk & 0xffff);
    }
}

// ---------------- fused spmm64+relu + gemm40 (final layer tables), bf16 weights ----------------
__global__ __launch_bounds__(256) void k_fs64_g40(const unsigned* __restrict__ G0b_in,
                                                  const unsigned char* __restrict__ g1_in,
                                                  const int* __restrict__ rowptr,
                                                  const int* __restrict__ csr_src,
                                                  const int* __restrict__ deg_src,
                                                  const int* __restrict__ maxdeg,
                                                  const float* __restrict__ W0,
                                                  const float* __restrict__ W1,
                                                  const float* __restrict__ b,
                                                  unsigned* __restrict__ G0b_out,
                                                  unsigned short* __restrict__ G1f8_out) {
    __shared__ unsigned sw0[64 * PAIRS40], sw1[64 * PAIRS40];   // 10 KB
    __shared__ float sh[32 * 64];                               // 8 KB -> 18 KB total
    int t = threadIdx.x;
    const float2* W02 = (const float2*)W0;
    const float2* W12 = (const float2*)W1;
    for (int k = t; k < 64 * PAIRS40; k += 256) {
        float2 w0 = W02[k], w1 = W12[k];
        sw0[k] = pack_bf16x2(w0.x, w0.y);
        sw1[k] = pack_bf16x2(w1.x, w1.y);
    }
    // ---- spmm part ----
    int waveId = t >> 6, lane = t & 63;
    int ch = lane & 7;
    int local = waveId * 8 + (lane >> 3);
    int node = blockIdx.x * 32 + local;
    float scale = 1.0f / (float)(*maxdeg);
    int e0 = rowptr[node], e1 = rowptr[node + 1];
    int octbase = lane & 56;
    vf2 acc[4];
    acc[0] = 0.f; acc[1] = 0.f; acc[2] = 0.f; acc[3] = 0.f;
    for (int e = e0; e < e1; e += 8) {
        int idx = csr_src[e + ch];
        #pragma unroll
        for (int j = 0; j < 8; j++) {
            int s = __shfl(idx, octbase | j);
            uint2 u = ((const uint2*)(g1_in + (size_t)s * 64))[ch];
            acc[0] += __builtin_amdgcn_cvt_pk_f32_fp8((int)u.x, false);
            acc[1] += __builtin_amdgcn_cvt_pk_f32_fp8((int)u.x, true);
            acc[2] += __builtin_amdgcn_cvt_pk_f32_fp8((int)u.y, false);
            acc[3] += __builtin_amdgcn_cvt_pk_f32_fp8((int)u.y, true);
        }
    }
    uint4 g = ((const uint4*)(G0b_in + (size_t)node * 32))[ch];
    float* shr = sh + local * 64 + ch * 8;
    shr[0] = fmaxf(bf_lo(g.x) - scale * acc[0].x, 0.f);
    shr[1] = fmaxf(bf_hi(g.x) - scale * acc[0].y, 0.f);
    shr[2] = fmaxf(bf_lo(g.y) - scale * acc[1].x, 0.f);
    shr[3] = fmaxf(bf_hi(g.y) - scale * acc[1].y, 0.f);
    shr[4] = fmaxf(bf_lo(g.z) - scale * acc[2].x, 0.f);
    shr[5] = fmaxf(bf_hi(g.z) - scale * acc[2].y, 0.f);
    shr[6] = fmaxf(bf_lo(g.w) - scale * acc[3].x, 0.f);
    shr[7] = fmaxf(bf_hi(g.w) - scale * acc[3].y, 0.f);
    if (blockIdx.x == 0 && t < 10) ((unsigned*)G1f8_out)[N_NODES * 10 + t] = 0;  // zero row (40B)
    __syncthreads();
    // ---- gemm part (64 -> 40) ----
    int c2 = t & 31, rg = t >> 5;
    if (c2 >= PAIRS40) return;
    int i0 = blockIdx.x * 32;
    float2 b2 = ((const float2*)b)[c2];
    float a0x[4], a0y[4], a1x[4], a1y[4];
    #pragma unroll
    for (int p = 0; p < 4; p++) { a0x[p] = b2.x; a0y[p] = b2.y; a1x[p] = 0.f; a1y[p] = 0.f; }
    #pragma unroll
    for (int k = 0; k < 64; k++) {
        unsigned u0 = sw0[k * PAIRS40 + c2], u1 = sw1[k * PAIRS40 + c2];
        float w0x = bf_lo(u0), w0y = bf_hi(u0), w1x = bf_lo(u1), w1y = bf_hi(u1);
        #pragma unroll
        for (int p = 0; p < 4; p++) {
            float hv = sh[(rg + 8 * p) * 64 + k];
            a0x[p] += hv * w0x; a0y[p] += hv * w0y;
            a1x[p] += hv * w1x; a1y[p] += hv * w1y;
        }
    }
    #pragma unroll
    for (int p = 0; p < 4; p++) {
        int row = i0 + rg + 8 * p;
        float nl = (float)deg_src[row] * scale - 1.0f;
        G0b_out[row * PAIRS40 + c2] = pack_bf16x2(a0x[p] + nl * a1x[p], a0y[p] + nl * a1y[p]);
        int pk = __builtin_amdgcn_cvt_pk_fp8_f32(a1x[p], a1y[p], 0, false);
        G1f8_out[row * PAIRS40 + c2] = (unsigned short)(pk & 0xffff);
    }
}

// ---------------- fused SpMM + log_softmax, 40 ch fp8, one octet per node ----------------
__global__ __launch_bounds__(256) void k_spmm40(const unsigned* __restrict__ G0b,
                                               const unsigned char* __restrict__ g1,
                                               const int* __restrict__ rowptr,
                                               const int* __restrict__ csr_src,
                                               const int* __restrict__ maxdeg,
                                               float* __restrict__ out) {
    int t = threadIdx.x;
    int waveId = t >> 6, lane = t & 63;
    int ch = lane & 7;
    bool act = ch < 5;
    int node = blockIdx.x * 32 + waveId * 8 + (lane >> 3);
    float scale = 1.0f / (float)(*maxdeg);
    int e0 = rowptr[node], e1 = rowptr[node + 1];
    int octbase = lane & 56;
    vf2 acc[4];
    acc[0] = 0.f; acc[1] = 0.f; acc[2] = 0.f; acc[3] = 0.f;
    for (int e = e0; e < e1; e += 8) {
        int idx = csr_src[e + ch];
        #pragma unroll
        for (int j = 0; j < 8; j++) {
            int s = __shfl(idx, octbase | j);
            if (act) {
                uint2 u = ((const uint2*)(g1 + (size_t)s * 40))[ch];
                acc[0] += __builtin_amdgcn_cvt_pk_f32_fp8((int)u.x, false);
                acc[1] += __builtin_amdgcn_cvt_pk_f32_fp8((int)u.x, true);
                acc[2] += __builtin_amdgcn_cvt_pk_f32_fp8((int)u.y, false);
                acc[3] += __builtin_amdgcn_cvt_pk_f32_fp8((int)u.y, true);
            }
        }
    }
    float v[8];
    float m = -INFINITY;
    if (act) {
        uint4 g = ((const uint4*)(G0b + (size_t)node * PAIRS40))[ch];
        v[0] = bf_lo(g.x) - scale * acc[0].x;
        v[1] = bf_hi(g.x) - scale * acc[0].y;
        v[2] = bf_lo(g.y) - scale * acc[1].x;
        v[3] = bf_hi(g.y) - scale * acc[1].y;
        v[4] = bf_lo(g.z) - scale * acc[2].x;
        v[5] = bf_hi(g.z) - scale * acc[2].y;
        v[6] = bf_lo(g.w) - scale * acc[3].x;
        v[7] = bf_hi(g.w) - scale * acc[3].y;
        #pragma unroll
        for (int q = 0; q < 8; q++) m = fmaxf(m, v[q]);
    }
    m = fmaxf(m, __shfl_xor(m, 1));
    m = fmaxf(m, __shfl_xor(m, 2));
    m = fmaxf(m, __shfl_xor(m, 4));
    float s = 0.f;
    if (act) {
        #pragma unroll
        for (int q = 0; q < 8; q++) s += __expf(v[q] - m);
    }
    s += __shfl_xor(s, 1);
    s += __shfl_xor(s, 2);
    s += __shfl_xor(s, 4);
    float ls = __logf(s);
    if (act) {
        float4 oA, oB;
        oA.x = v[0] - m - ls; oA.y = v[1] - m - ls; oA.z = v[2] - m - ls; oA.w = v[3] - m - ls;
        oB.x = v[4] - m - ls; oB.y = v[5] - m - ls; oB.z = v[6] - m - ls; oB.w = v[7] - m - ls;
        float4* o4 = (float4*)(out + (size_t)node * 40);
        o4[ch * 2] = oA;
        o4[ch * 2 + 1] = oB;
    }
}

// ---------------- launch ----------------

extern "C" void kernel_launch(void* const* d_in, const int* in_sizes, int n_in,
                              void* d_out, int out_size, void* d_ws, size_t ws_size,
                              hipStream_t stream) {
    const float* x   = (const float*)d_in[0];
    const int* ei    = (const int*)d_in[1];
    const int* src   = ei;
    const int* dst   = ei + N_EDGES;
    const float* W0_0 = (const float*)d_in[2];
    const float* W1_0 = (const float*)d_in[3];
    const float* b_0  = (const float*)d_in[4];
    const float* W0_1 = (const float*)d_in[5];
    const float* W1_1 = (const float*)d_in[6];
    const float* b_1  = (const float*)d_in[7];
    const float* W0_2 = (const float*)d_in[8];
    const float* W1_2 = (const float*)d_in[9];
    const float* b_2  = (const float*)d_in[10];
    float* outp = (float*)d_out;

    // workspace layout (int offsets)
    int* ip = (int*)d_ws;
    int* deg_src  = ip;                      // N
    int* rowptr   = ip + 100000;             // N+1 (padded region to 100032)
    int* blocksum = ip + 200064;             // 128
    int* maxdeg   = ip + 200192;             // 1 (pad 64)
    int* csr_src  = ip + 200256;             // padded CSR <= E + 7N = 2.3M (2.5M reserved)
    int* Hs       = ip + 2700256;            // 4.19M
    int* Hd       = ip + 6894560;            // 4.19M
    unsigned* GA0 = (unsigned*)(ip + 11088864);          // N*32 uints
    unsigned short* GA1 = (unsigned short*)(ip + 14288864); // N*32+32 ushorts
    unsigned* GB0 = (unsigned*)(ip + 15888928);          // N*32 uints
    unsigned short* GB1 = (unsigned short*)(ip + 19088928); // N*32+32 ushorts

    (void)hipMemsetAsync(maxdeg, 0, sizeof(int), stream);

    k_hist<<<dim3(NC, NR_H, 2), 1024, 0, stream>>>(src, dst, Hs, Hd);
    k_scan1<<<SCAN_NBLK, SCAN_BLOCK, 0, stream>>>(Hs, Hd, rowptr, blocksum, deg_src, maxdeg);
    k_finalize<<<SCAN_NBLK, SCAN_BLOCK, 0, stream>>>(blocksum, rowptr, Hd, csr_src);
    k_fill2<<<dim3(NC, NR_F), 1024, 0, stream>>>(src, dst, Hd, csr_src);

    const int GS = N_NODES / 32;   // 3125 blocks

    // L0: x -> GA (gemm64 layer 0)
    k_gemm64<<<GS, 256, 0, stream>>>(x, W0_0, W1_0, b_0, deg_src, maxdeg, GA0, GA1);
    // L1: spmm(GA) + relu + gemm64 layer1 -> GB
    k_fs64_g64<<<GS, 256, 0, stream>>>(GA0, (const unsigned char*)GA1, rowptr, csr_src,
                                       deg_src, maxdeg, W0_1, W1_1, b_1, GB0, GB1);
    // L2: spmm(GB) + relu + gemm40 layer2 -> GA (40-ch layout)
    k_fs64_g40<<<GS, 256, 0, stream>>>(GB0, (const unsigned char*)GB1, rowptr, csr_src,
                                       deg_src, maxdeg, W0_2, W1_2, b_2, GA0, GA1);
    // L3: spmm40 + log_softmax -> out
    k_spmm40<<<GS, 256, 0, stream>>>(GA0, (const unsigned char*)GA1, rowptr, csr_src, maxdeg, outp);
}